// Round 10
// baseline (118.602 us; speedup 1.0000x reference)
//
#include <hip/hip_runtime.h>
#include <math.h>

// Fixed problem dims from setup_inputs()
#define BATCH 2
#define C 64
#define HIN 128
#define WIN 128
#define HW (HIN * WIN)
#define OH 256
#define OW 256

#define BLK 256
#define PIX 64    // pixels per block (64 consecutive ox in one oy row)
#define SC 16     // channels per thread-slice (4 slices)
#define ASTR 72   // act row stride in shorts (144 B rows, 16B aligned)
#define YHSTR 17  // y6 row stride in floats (odd -> conflict-free)
#define YSTR 33   // y32 row stride in floats (odd -> conflict-free)
#define OSTR 68   // ofs row stride in floats (272 B, 16B aligned)

// ws bf16 layout (shorts):
//  [    0.. 4095] w1k [n][64]   (w1[n][4+k])
//  [ 4096.. 8191] w2k [n][64]
//  [ 8192..10239] wcm [32][64]  (row eo=e*8+d, k-contig)
//  [10240..12287] wex [256][8]  (row e*64+c, k=d)
//  [12288..13311] whd [16][64]  (rows 0-1 wo, 2-5 wr, 6-15 zero)
#define WS_W2  4096
#define WS_WC  8192
#define WS_WE  10240
#define WS_WH  12288
#define WS_TOT 13312

// Round-10: paired-corner gathers. The two x-corners of each bilinear tap
// are adjacent (xi1=xi0+1) except at clamped borders where the stray
// corner's weight is zero (except left-edge xi0=xi1=0, handled by selx).
// Each row-pair is ONE 8-byte load from base=min(xi0,WIN-2) + 2 cndmask:
//   hisel = (xi0>base)  -> l00 = a.y else a.x
//   selx  = (xi1==xi0)  -> l10 = l00 else a.y
// The load type is a plain struct{float x,y;} (alignof 4): clang emits a
// single global_load_dwordx2 when unaligned global access is legal, else
// two dword loads -- correct either way. Halves gather VMEM (64->32 per
// thread per sampling phase). Everything else as round 9 (MFMA convs,
// heads-GEMM, prep-packed bf16 weights).

typedef __attribute__((ext_vector_type(8))) short bf16x8;
typedef __attribute__((ext_vector_type(4))) float f32x4;

struct f2u { float x, y; };   // alignof(4) -> unaligned-safe pair load

__device__ __forceinline__ unsigned short f2bf(float f) {
    unsigned u = __float_as_uint(f);
    u += 0x7FFFu + ((u >> 16) & 1u);          // round-to-nearest-even
    return (unsigned short)(u >> 16);
}

// Pair-based bilinear setup: row base addresses + selects + weights.
__device__ __forceinline__ void bilin_pair(float gx, float gy,
    int& r0, int& r1, bool& hisel, bool& selx,
    float& w00, float& w10, float& w01, float& w11)
{
    const float fx = ((gx + 1.0f) * WIN - 1.0f) * 0.5f;
    const float fy = ((gy + 1.0f) * HIN - 1.0f) * 0.5f;
    const float x0 = floorf(fx), y0 = floorf(fy);
    const float wx1 = fx - x0, wx0 = 1.0f - wx1;
    const float wy1 = fy - y0, wy0 = 1.0f - wy1;
    const float x1 = x0 + 1.0f, y1 = y0 + 1.0f;
    const bool vx0 = (x0 >= 0.0f) && (x0 <= (float)(WIN - 1));
    const bool vx1 = (x1 >= 0.0f) && (x1 <= (float)(WIN - 1));
    const bool vy0 = (y0 >= 0.0f) && (y0 <= (float)(HIN - 1));
    const bool vy1 = (y1 >= 0.0f) && (y1 <= (float)(HIN - 1));
    const int xi0 = (int)fminf(fmaxf(x0, 0.0f), (float)(WIN - 1));
    const int xi1 = (int)fminf(fmaxf(x1, 0.0f), (float)(WIN - 1));
    const int yi0 = (int)fminf(fmaxf(y0, 0.0f), (float)(HIN - 1));
    const int yi1 = (int)fminf(fmaxf(y1, 0.0f), (float)(HIN - 1));
    w00 = wx0 * wy0 * ((vx0 && vy0) ? 1.0f : 0.0f);
    w10 = wx1 * wy0 * ((vx1 && vy0) ? 1.0f : 0.0f);
    w01 = wx0 * wy1 * ((vx0 && vy1) ? 1.0f : 0.0f);
    w11 = wx1 * wy1 * ((vx1 && vy1) ? 1.0f : 0.0f);
    const int base = min(xi0, WIN - 2);
    hisel = (xi0 > base);       // only when xi0==WIN-1
    selx  = (xi1 == xi0);       // clamp collision (left or right edge)
    r0 = yi0 * WIN + base;
    r1 = yi1 * WIN + base;
}

__global__ __launch_bounds__(256) void prep_kernel(
    const float* __restrict__ wcm, const float* __restrict__ wex,
    const float* __restrict__ w1,  const float* __restrict__ w2,
    const float* __restrict__ wr,  const float* __restrict__ wo,
    unsigned short* __restrict__ wsb)
{
    const int i = blockIdx.x * 256 + threadIdx.x;
    if (i >= WS_TOT) return;
    float v = 0.0f;
    if (i < WS_W2) {                       // w1k
        const int n = i >> 6, k = i & 63;
        v = w1[n * (C + 4) + 4 + k];
    } else if (i < WS_WC) {                // w2k
        v = w2[i - WS_W2];
    } else if (i < WS_WE) {                // wcm
        v = wcm[i - WS_WC];
    } else if (i < WS_WH) {                // wex
        v = wex[i - WS_WE];
    } else {                               // whd (zero-padded to 16 rows)
        const int j = i - WS_WH;
        const int n = j >> 6, k = j & 63;
        v = (n < 2) ? wo[n * C + k] : ((n < 6) ? wr[(n - 2) * C + k] : 0.0f);
    }
    wsb[i] = f2bf(v);
}

__global__ __launch_bounds__(BLK, 4) void scab_kernel(
    const float* __restrict__ x,    // (B, C, HIN, WIN)
    const float* __restrict__ w1,   // (64, 68)  (coord cols + bias fold)
    const float* __restrict__ b1,   // (64)
    const float* __restrict__ b2,   // (64)
    const float* __restrict__ br,   // (4)
    const float* __restrict__ bo,   // (2)
    const unsigned short* __restrict__ wsb,  // pre-packed bf16 weights
    float* __restrict__ out)        // (B, C, OH, OW)
{
    __shared__ __align__(16) short act[PIX * ASTR];   // 9216 B
    __shared__ __align__(16) float red[PIX * OSTR];   // 17408 B

    const int tid  = threadIdx.x;
    const int lane = tid & 63;                                  // pixel within block
    const int s    = __builtin_amdgcn_readfirstlane(tid >> 6);  // slice == wave id
    const int cb   = s * SC;
    const int l15  = lane & 15;
    const int quad = lane >> 4;
    const int nn   = cb + l15;                                  // my MFMA out-col

    const int gp = blockIdx.x * PIX + lane;
    const int ox = gp & (OW - 1);
    const int oy = (gp >> 8) & (OH - 1);
    const int bb = gp >> 16;

    // ---- base grid (fp32, matches reference) ----
    const float gx = ((ox + 0.5f) * 0.5f - 0.5f) * (2.0f / (WIN - 1)) - 1.0f;
    const float gy = ((oy + 0.5f) * 0.5f - 0.5f) * (2.0f / (HIN - 1)) - 1.0f;

    const float* __restrict__ xb = x + bb * (C * HW);

    // ===== B-frags: single dwordx4 loads from pre-packed ws =====
    const int nt1  = s & 1;                  // GEMM-1 n-tile of this wave
    const int eo_g = nt1 * 16 + l15;         // GEMM-1 out index (e*8+d)
    bf16x8 bw1[2], bw2[2], bwc[2], bhd[2], bwe;
    #pragma unroll
    for (int ks = 0; ks < 2; ++ks) {
        bw1[ks] = *(const bf16x8*)(wsb +         nn   * 64 + ks * 32 + quad * 8);
        bw2[ks] = *(const bf16x8*)(wsb + WS_W2 + nn   * 64 + ks * 32 + quad * 8);
        bwc[ks] = *(const bf16x8*)(wsb + WS_WC + eo_g * 64 + ks * 32 + quad * 8);
        bhd[ks] = *(const bf16x8*)(wsb + WS_WH + l15  * 64 + ks * 32 + quad * 8);
    }
    bwe = *(const bf16x8*)(wsb + WS_WE + (quad * C + nn) * 8);

    // ===== phase 1: sampling-1 paired gathers (my 16 ch) -> bf16 act =====
    {
        int r0, r1;
        bool hisel, selx;
        float w00, w10, w01, w11;
        bilin_pair(gx, gy, r0, r1, hisel, selx, w00, w10, w01, w11);
        bf16x8 v0, v1;
        #pragma unroll
        for (int kk = 0; kk < SC; kk += 4) {
            f2u a0[4], a1[4];
            #pragma unroll
            for (int k = 0; k < 4; ++k) {
                const float* __restrict__ xc = xb + (cb + kk + k) * HW;
                a0[k] = *(const f2u*)(xc + r0);
                a1[k] = *(const f2u*)(xc + r1);
            }
            #pragma unroll
            for (int k = 0; k < 4; ++k) {
                const float l00 = hisel ? a0[k].y : a0[k].x;
                const float l10 = selx ? l00 : a0[k].y;
                const float l01 = hisel ? a1[k].y : a1[k].x;
                const float l11 = selx ? l01 : a1[k].y;
                const float pf = l00*w00 + l10*w10 + l01*w01 + l11*w11;
                const short b = (short)f2bf(pf);
                if (kk + k < 8) v0[kk + k] = b; else v1[kk + k - 8] = b;
            }
        }
        *(bf16x8*)&act[lane * ASTR + cb]     = v0;
        *(bf16x8*)&act[lane * ASTR + cb + 8] = v1;
    }
    __syncthreads();

    // ===== phase 2: conv1 via MFMA; coords+bias folded into C-init =====
    const float coor_h = (oy & 1) ? 0.25f : -0.25f;
    f32x4 acc[4];
    {
        const float4 wh = *(const float4*)(w1 + nn * (C + 4));   // w1[n][0..3]
        const float qn = b1[nn] + (wh.x + wh.y) * 0.5f + wh.z * coor_h;
        const float e0 = qn - 0.25f * wh.w;    // even pixel rows (reg 0,2)
        const float e1 = qn + 0.25f * wh.w;    // odd  pixel rows (reg 1,3)
        #pragma unroll
        for (int t = 0; t < 4; ++t) acc[t] = (f32x4){e0, e1, e0, e1};
    }
    #pragma unroll
    for (int t = 0; t < 4; ++t) {
        #pragma unroll
        for (int ks = 0; ks < 2; ++ks) {
            const bf16x8 af = *(const bf16x8*)&act[(t*16 + l15) * ASTR + ks*32 + quad*8];
            acc[t] = __builtin_amdgcn_mfma_f32_16x16x32_bf16(af, bw1[ks], acc[t], 0, 0, 0);
        }
    }
    __syncthreads();
    #pragma unroll
    for (int t = 0; t < 4; ++t)
        #pragma unroll
        for (int r = 0; r < 4; ++r)
            act[(t*16 + quad*4 + r) * ASTR + nn] = (short)f2bf(fmaxf(acc[t][r], 0.0f));
    __syncthreads();

    // ===== phase 3: conv2 via MFMA =====
    {
        const float b2n = b2[nn];
        #pragma unroll
        for (int t = 0; t < 4; ++t) acc[t] = (f32x4){b2n, b2n, b2n, b2n};
    }
    #pragma unroll
    for (int t = 0; t < 4; ++t) {
        #pragma unroll
        for (int ks = 0; ks < 2; ++ks) {
            const bf16x8 af = *(const bf16x8*)&act[(t*16 + l15) * ASTR + ks*32 + quad*8];
            acc[t] = __builtin_amdgcn_mfma_f32_16x16x32_bf16(af, bw2[ks], acc[t], 0, 0, 0);
        }
    }
    __syncthreads();
    #pragma unroll
    for (int t = 0; t < 4; ++t)
        #pragma unroll
        for (int r = 0; r < 4; ++r)
            act[(t*16 + quad*4 + r) * ASTR + nn] = (short)f2bf(fmaxf(acc[t][r], 0.0f));
    __syncthreads();

    // ===== phase 4: heads via MFMA (wave s = m-tile s; n<6 used) =====
    {
        f32x4 yac = (f32x4){0.0f, 0.0f, 0.0f, 0.0f};
        #pragma unroll
        for (int ks = 0; ks < 2; ++ks) {
            const bf16x8 af = *(const bf16x8*)&act[(s*16 + l15) * ASTR + ks*32 + quad*8];
            yac = __builtin_amdgcn_mfma_f32_16x16x32_bf16(af, bhd[ks], yac, 0, 0, 0);
        }
        #pragma unroll
        for (int r = 0; r < 4; ++r)
            red[(s*16 + quad*4 + r) * YHSTR + l15] = yac[r];
    }
    __syncthreads();

    // ===== phase 5: offsets/gates from y6, then sampling-2 paired gathers =====
    const float* __restrict__ yp = &red[lane * YHSTR];
    const float offx = bo[0] + yp[0];
    const float offy = bo[1] + yp[1];
    const float rg0 = 1.0f / (1.0f + __expf(-(br[0] + yp[2])));
    const float rg1 = 1.0f / (1.0f + __expf(-(br[1] + yp[3])));
    const float rg2 = 1.0f / (1.0f + __expf(-(br[2] + yp[4])));
    const float rg3 = 1.0f / (1.0f + __expf(-(br[3] + yp[5])));

    float f[SC];
    {
        int r0, r1;
        bool hisel, selx;
        float w00, w10, w01, w11;
        bilin_pair(gx + offx * (2.0f / (WIN - 1)),
                   gy + offy * (2.0f / (HIN - 1)),
                   r0, r1, hisel, selx, w00, w10, w01, w11);
        bf16x8 v0, v1;
        #pragma unroll
        for (int kk = 0; kk < SC; kk += 4) {
            f2u a0[4], a1[4];
            #pragma unroll
            for (int k = 0; k < 4; ++k) {
                const float* __restrict__ xc = xb + (cb + kk + k) * HW;
                a0[k] = *(const f2u*)(xc + r0);
                a1[k] = *(const f2u*)(xc + r1);
            }
            #pragma unroll
            for (int k = 0; k < 4; ++k) {
                const float l00 = hisel ? a0[k].y : a0[k].x;
                const float l10 = selx ? l00 : a0[k].y;
                const float l01 = hisel ? a1[k].y : a1[k].x;
                const float l11 = selx ? l01 : a1[k].y;
                const float fc = l00*w00 + l10*w10 + l01*w01 + l11*w11;
                f[kk + k] = fc;
                const short b = (short)f2bf(fc);
                if (kk + k < 8) v0[kk + k] = b; else v1[kk + k - 8] = b;
            }
        }
        *(bf16x8*)&act[lane * ASTR + cb]     = v0;   // overwrite emb
        *(bf16x8*)&act[lane * ASTR + cb + 8] = v1;
    }
    __syncthreads();   // act(fea0) visible; all y6 reads done

    // ===== phase 6: GEMM-1  y[pix][eo] = fea0 x wcm^T  (2 m-tiles/wave) =====
    {
        const int mb = (s >> 1) * 2;
        #pragma unroll
        for (int mi = 0; mi < 2; ++mi) {
            const int mt = mb + mi;
            f32x4 yac = (f32x4){0.0f, 0.0f, 0.0f, 0.0f};
            #pragma unroll
            for (int ks = 0; ks < 2; ++ks) {
                const bf16x8 af = *(const bf16x8*)&act[(mt*16 + l15) * ASTR + ks*32 + quad*8];
                yac = __builtin_amdgcn_mfma_f32_16x16x32_bf16(af, bwc[ks], yac, 0, 0, 0);
            }
            #pragma unroll
            for (int r = 0; r < 4; ++r)
                red[(mt*16 + quad*4 + r) * YSTR + nt1*16 + l15] = yac[r];
        }
    }
    __syncthreads();

    // ===== phase 7: per-pixel gate fold: comp[d], t[ed] -> bf16 act[pix][0..31] =====
    {
        float comp[8];
        const float* __restrict__ yr = &red[lane * YSTR];
        #pragma unroll
        for (int d = 0; d < 8; ++d) {
            float v = rg0 * yr[d];
            v = fmaf(rg1, yr[8 + d],  v);
            v = fmaf(rg2, yr[16 + d], v);
            v = fmaf(rg3, yr[24 + d], v);
            comp[d] = v;
        }
        bf16x8 t0, t1, t2, t3;
        #pragma unroll
        for (int d = 0; d < 8; ++d) {
            t0[d] = (short)f2bf(rg0 * comp[d]);
            t1[d] = (short)f2bf(rg1 * comp[d]);
            t2[d] = (short)f2bf(rg2 * comp[d]);
            t3[d] = (short)f2bf(rg3 * comp[d]);
        }
        // act reads for GEMM-1 completed before the post-ph6 barrier; t
        // writes (act) and y reads (red) touch different arrays. Safe.
        *(bf16x8*)&act[lane * ASTR + 0]  = t0;
        *(bf16x8*)&act[lane * ASTR + 8]  = t1;
        *(bf16x8*)&act[lane * ASTR + 16] = t2;
        *(bf16x8*)&act[lane * ASTR + 24] = t3;
    }
    __syncthreads();

    // ===== phase 8: GEMM-2  expand[pix][c] = t x wexR^T  (4 m-tiles/wave) =====
    #pragma unroll
    for (int t = 0; t < 4; ++t) {
        f32x4 oac = (f32x4){0.0f, 0.0f, 0.0f, 0.0f};
        const bf16x8 af = *(const bf16x8*)&act[(t*16 + l15) * ASTR + quad*8];
        oac = __builtin_amdgcn_mfma_f32_16x16x32_bf16(af, bwe, oac, 0, 0, 0);
        #pragma unroll
        for (int r = 0; r < 4; ++r)
            red[(t*16 + quad*4 + r) * OSTR + nn] = oac[r];
    }
    __syncthreads();

    // ===== phase 9: residual + coalesced store (pixel=lane, my 16 ch) =====
    float* __restrict__ ob = out + bb * (C * OH * OW) + oy * OW + ox;
    const float* __restrict__ orow = &red[lane * OSTR + cb];
    #pragma unroll
    for (int kk = 0; kk < SC; kk += 4) {
        const float4 e4 = *(const float4*)(orow + kk);
        ob[(cb + kk + 0) * (OH * OW)] = f[kk + 0] + e4.x;
        ob[(cb + kk + 1) * (OH * OW)] = f[kk + 1] + e4.y;
        ob[(cb + kk + 2) * (OH * OW)] = f[kk + 2] + e4.z;
        ob[(cb + kk + 3) * (OH * OW)] = f[kk + 3] + e4.w;
    }
}

extern "C" void kernel_launch(void* const* d_in, const int* in_sizes, int n_in,
                              void* d_out, int out_size, void* d_ws, size_t ws_size,
                              hipStream_t stream) {
    const float* x   = (const float*)d_in[0];
    const float* wcm = (const float*)d_in[1];
    const float* wex = (const float*)d_in[2];
    const float* w1  = (const float*)d_in[3];
    const float* b1  = (const float*)d_in[4];
    const float* w2  = (const float*)d_in[5];
    const float* b2  = (const float*)d_in[6];
    const float* wr  = (const float*)d_in[7];
    const float* br  = (const float*)d_in[8];
    const float* wo  = (const float*)d_in[9];
    const float* bo  = (const float*)d_in[10];
    float* out = (float*)d_out;
    unsigned short* wsb = (unsigned short*)d_ws;

    // prep: pack weights to bf16 in ws (same work every call; stream-ordered)
    prep_kernel<<<(WS_TOT + 255) / 256, 256, 0, stream>>>(wcm, wex, w1, w2, wr, wo, wsb);

    const int total  = BATCH * OH * OW;    // 131072 pixels
    const int blocks = total / PIX;        // 2048 blocks of 256 threads
    scab_kernel<<<blocks, BLK, 0, stream>>>(x, w1, b1, b2, br, bo, wsb, out);
}